// Round 13
// baseline (84.519 us; speedup 1.0000x reference)
//
#include <hip/hip_runtime.h>
#include <hip/hip_bf16.h>

// Problem constants (B=8, S=4096, D=128 per reference setup_inputs)
#define B_ 8
#define S_ 4096
#define D_ 128
#define C_ 256                 // chunk length
#define NC 16                  // chunks per batch = S_/C_

typedef __attribute__((ext_vector_type(8))) short bf16x8;   // MFMA A/B frag (4 VGPRs)
typedef __attribute__((ext_vector_type(4))) float f32x4;    // 16x16 MFMA C/D frag
typedef __attribute__((ext_vector_type(4))) unsigned u32x4;

// f32 -> bf16 round-to-nearest-even
static __device__ __forceinline__ unsigned short f2bf(float x) {
    unsigned u = __float_as_uint(x);
    u += 0x7fffu + ((u >> 16) & 1u);
    return (unsigned short)(u >> 16);
}
static __device__ __forceinline__ float bf2f(unsigned short h) {
    return __uint_as_float(((unsigned)h) << 16);
}

// async global -> LDS, 16 bytes per lane (dest = wave-uniform base + lane*16)
typedef const __attribute__((address_space(1))) unsigned int* gas_ptr;
typedef __attribute__((address_space(3))) unsigned int* las_ptr;
static __device__ __forceinline__ void load_lds16(const unsigned short* g, unsigned short* l) {
    __builtin_amdgcn_global_load_lds((gas_ptr)(const void*)g, (las_ptr)(void*)l, 16, 0, 0);
}

#define WAIT_VMCNT_0 do { asm volatile("s_waitcnt vmcnt(0)" ::: "memory"); \
                          __builtin_amdgcn_sched_barrier(0); } while (0)
#define BARRIER      do { __builtin_amdgcn_s_barrier(); \
                          __builtin_amdgcn_sched_barrier(0); } while (0)

// ---------------------------------------------------------------------------
// prep: [0,2048) RoPE Q,K -> Qr,Kr bf16 (natural [t][d])
//       [2048,2560) V transpose -> Vt bf16 [d][t]
//       [2560,3072) K transpose + RoPE -> Kt bf16 [d][t]
// ---------------------------------------------------------------------------
__global__ __launch_bounds__(256) void prep(const float* __restrict__ Q,
                                            const float* __restrict__ K,
                                            const float* __restrict__ V,
                                            unsigned short* __restrict__ Qr,
                                            unsigned short* __restrict__ Kr,
                                            unsigned short* __restrict__ Kt,
                                            unsigned short* __restrict__ Vt) {
    __shared__ float smf[64 * 130];               // f32 tile; V branch reuses as ushort
    const int bid = blockIdx.x;
    const int tid = threadIdx.x;
    if (bid < 2048) {
        int e = bid * 256 + tid;                  // 0 .. 8*4096*16-1
        int t = e & 15;
        int s = (e >> 4) & (S_ - 1);
        int b = e >> 16;
        size_t base = ((size_t)(b * S_ + s)) * D_;
        int d0 = t * 4;
        float qa[4], qb[4], ka[4], kb[4];
        *(float4*)qa = *(const float4*)(Q + base + d0);
        *(float4*)qb = *(const float4*)(Q + base + d0 + 64);
        *(float4*)ka = *(const float4*)(K + base + d0);
        *(float4*)kb = *(const float4*)(K + base + d0 + 64);
        unsigned short ql[4], qh[4], kl[4], kh[4];
        #pragma unroll
        for (int jj = 0; jj < 4; ++jj) {
            float invf = exp2f(-0.20762050f * (float)(d0 + jj));  // 10000^{-(d0+jj)/64}
            float ang = (float)s * invf;
            float sn, cs;
            __sincosf(ang, &sn, &cs);
            ql[jj] = f2bf(qa[jj] * cs - qb[jj] * sn);
            qh[jj] = f2bf(qb[jj] * cs + qa[jj] * sn);
            kl[jj] = f2bf(ka[jj] * cs - kb[jj] * sn);
            kh[jj] = f2bf(kb[jj] * cs + ka[jj] * sn);
        }
        *reinterpret_cast<ushort4*>(Qr + base + d0)      = ushort4{ql[0], ql[1], ql[2], ql[3]};
        *reinterpret_cast<ushort4*>(Qr + base + d0 + 64) = ushort4{qh[0], qh[1], qh[2], qh[3]};
        *reinterpret_cast<ushort4*>(Kr + base + d0)      = ushort4{kl[0], kl[1], kl[2], kl[3]};
        *reinterpret_cast<ushort4*>(Kr + base + d0 + 64) = ushort4{kh[0], kh[1], kh[2], kh[3]};
    } else if (bid < 2560) {
        // V [B][S][D] f32 -> Vt [B][D][S] bf16
        unsigned short* tile = (unsigned short*)smf;
        int b2 = bid - 2048;                      // 0..511
        int b  = b2 >> 6;
        int t0 = (b2 & 63) * 64;
        #pragma unroll
        for (int it = 0; it < 32; ++it) {
            int e = it * 256 + tid;
            int tl = e >> 7, d = e & 127;
            tile[tl * 130 + d] = f2bf(V[((size_t)(b * S_ + t0 + tl)) * D_ + d]);
        }
        __syncthreads();
        #pragma unroll
        for (int it = 0; it < 32; ++it) {
            int e = it * 256 + tid;
            int d = e >> 6, tl = e & 63;
            Vt[((size_t)(b * D_ + d)) * S_ + t0 + tl] = tile[tl * 130 + d];
        }
    } else {
        // K [B][S][D] f32 -(RoPE)-> Kt [B][D][S] bf16
        int b2 = bid - 2560;                      // 0..511
        int b  = b2 >> 6;
        int t0 = (b2 & 63) * 64;
        #pragma unroll
        for (int it = 0; it < 32; ++it) {
            int e = it * 256 + tid;
            int tl = e >> 7, d = e & 127;
            smf[tl * 130 + d] = K[((size_t)(b * S_ + t0 + tl)) * D_ + d];
        }
        __syncthreads();
        #pragma unroll
        for (int it = 0; it < 32; ++it) {
            int e = it * 256 + tid;
            int d = e >> 6, tl = e & 63;
            float invf = exp2f(-0.20762050f * (float)(d & 63));
            float ang = (float)(t0 + tl) * invf;
            float sn, cs;
            __sincosf(ang, &sn, &cs);
            float x = smf[tl * 130 + d];
            float y = (d < 64) ? (x * cs - smf[tl * 130 + d + 64] * sn)
                               : (x * cs + smf[tl * 130 + d - 64] * sn);
            Kt[((size_t)(b * D_ + d)) * S_ + t0 + tl] = f2bf(y);
        }
    }
}

// ---------------------------------------------------------------------------
// pass1: per-chunk partials P1[b][c] = Kr_c^T . V_c  (D x D, f32)
//   grid 128 = 8 b x 16 c; 4 waves, wave w owns d-rows [32w, 32w+32).
//   A = Kt (lane: A[row=d][k=t], 8 consecutive t), B = Vt (B[k=t][col=d']).
// ---------------------------------------------------------------------------
__global__ __launch_bounds__(256) void pass1(const unsigned short* __restrict__ Kt,
                                             const unsigned short* __restrict__ Vt,
                                             float* __restrict__ P1) {
    const int b = blockIdx.x >> 4;
    const int c = blockIdx.x & 15;
    const int tid = threadIdx.x;
    const int w = tid >> 6;
    const int l = tid & 63;
    const int g = l >> 4;
    const int n = l & 15;

    f32x4 acc[2][8];
    #pragma unroll
    for (int dr = 0; dr < 2; ++dr)
        #pragma unroll
        for (int dc = 0; dc < 8; ++dc) acc[dr][dc] = f32x4{0.f, 0.f, 0.f, 0.f};

    const size_t tbase = (size_t)c * C_ + 8 * g;
    #pragma unroll
    for (int ki = 0; ki < 8; ++ki) {
        bf16x8 a[2];
        #pragma unroll
        for (int dr = 0; dr < 2; ++dr)
            a[dr] = *reinterpret_cast<const bf16x8*>(
                Kt + ((size_t)(b * D_ + w * 32 + dr * 16 + n)) * S_ + tbase + ki * 32);
        #pragma unroll
        for (int dc = 0; dc < 8; ++dc) {
            const bf16x8 bf = *reinterpret_cast<const bf16x8*>(
                Vt + ((size_t)(b * D_ + dc * 16 + n)) * S_ + tbase + ki * 32);
            acc[0][dc] = __builtin_amdgcn_mfma_f32_16x16x32_bf16(a[0], bf, acc[0][dc], 0, 0, 0);
            acc[1][dc] = __builtin_amdgcn_mfma_f32_16x16x32_bf16(a[1], bf, acc[1][dc], 0, 0, 0);
        }
    }

    float* out = P1 + (size_t)(b * NC + c) * D_ * D_;
    #pragma unroll
    for (int dr = 0; dr < 2; ++dr)
        #pragma unroll
        for (int dc = 0; dc < 8; ++dc)
            #pragma unroll
            for (int rr = 0; rr < 4; ++rr)
                out[(size_t)(w * 32 + dr * 16 + 4 * g + rr) * D_ + dc * 16 + n]
                    = acc[dr][dc][rr];
}

// ---------------------------------------------------------------------------
// prefix: exclusive prefix over chunks; emit H^T as bf16 hi+lo.
//   thread <-> (b,d,d'); HT layout [b][c][d'][d].
// ---------------------------------------------------------------------------
__global__ __launch_bounds__(256) void prefix(const float* __restrict__ P1,
                                              unsigned short* __restrict__ HhiT,
                                              unsigned short* __restrict__ HloT) {
    int gid = blockIdx.x * 256 + threadIdx.x;     // 0 .. 131071
    int d  = gid & 127;
    int dp = (gid >> 7) & 127;
    int b  = gid >> 14;
    float run = 0.f;
    #pragma unroll
    for (int c = 0; c < NC; ++c) {
        unsigned short hi = f2bf(run);
        float rem = run - bf2f(hi);
        size_t idx = ((size_t)(b * NC + c) * D_ + dp) * D_ + d;
        HhiT[idx] = hi;
        HloT[idx] = f2bf(rem);
        run += P1[((size_t)(b * NC + c) * D_ + d) * D_ + dp];
    }
}

// ---------------------------------------------------------------------------
// pass2: O_c = Qr_c . H_c (inter, hi+lo)  +  causal(Qr_c.Kr_c^T).V_c (intra).
//   512 blocks = 8 b x 16 c x 4 sub-blocks (64 q-rows each; heavy-first).
//   4 waves x 16 rows (r10-verified body). Intra: <=4 K/V tiles staged in
//   single-buffered LDS (32KB -> 4 blocks/CU at VGPR<=128). No atomics.
// MFMA 16x16x32 bf16 layouts (verified rounds 1-10):
//   A: lane l holds A[row=l&15][k=8*(l>>4)+j]; B: B[k=8*(l>>4)+j][col=l&15]
//   C/D: lane,reg holds D[row=4*(l>>4)+reg][col=l&15]
// ---------------------------------------------------------------------------
__global__ __launch_bounds__(256, 4) void pass2(const unsigned short* __restrict__ Qr,
                                                const unsigned short* __restrict__ Kr,
                                                const unsigned short* __restrict__ Vt,
                                                const unsigned short* __restrict__ HhiT,
                                                const unsigned short* __restrict__ HloT,
                                                float* __restrict__ Out) {
    __shared__ unsigned short Kb[64 * 128];       // [t][d] swizzled chunks, 16KB
    __shared__ unsigned short Vb[128 * 64];       // [d][t] swizzled chunks, 16KB

    const int bid = blockIdx.x;
    const int pp = 3 - (bid >> 7);                // sub-block 0..3, heavy first
    const int r2 = bid & 127;
    const int b  = r2 & 7;
    const int c  = r2 >> 3;                       // chunk 0..15
    const int qg = c * 4 + pp;                    // global 64-row q-tile index

    const int tid = threadIdx.x;
    const int wv = tid >> 6;
    const int l  = tid & 63;
    const int g  = l >> 4;
    const int n  = l & 15;

    // K LDS chunk (t,cc) <- global chunk (t, cc^(t&15)); V chunk (d,cc) <- cc^(d&7)
    auto stage = [&](int tg) {
        const unsigned short* kbase = Kr + ((size_t)(b * S_ + tg * 64)) * D_;
        #pragma unroll
        for (int i = 0; i < 4; ++i) {
            int ci = i * 256 + tid;
            int t = ci >> 4, cc = ci & 15;
            load_lds16(kbase + t * D_ + ((cc ^ (t & 15)) * 8), &Kb[ci * 8]);
        }
        const unsigned short* vbase = Vt + (size_t)b * D_ * S_ + (size_t)tg * 64;
        #pragma unroll
        for (int i = 0; i < 4; ++i) {
            int ci = i * 256 + tid;
            int d = ci >> 3, cc = ci & 7;
            load_lds16(vbase + (size_t)d * S_ + ((cc ^ (d & 7)) * 8), &Vb[ci * 8]);
        }
    };

    // hoist Q fragments (16 rows/wave)
    bf16x8 qf[4];
    {
        const unsigned short* qp =
            Qr + ((size_t)(b * S_ + qg * 64 + wv * 16 + n)) * D_ + 8 * g;
        #pragma unroll
        for (int ks = 0; ks < 4; ++ks)
            qf[ks] = *reinterpret_cast<const bf16x8*>(qp + ks * 32);
    }

    f32x4 o[8];
    #pragma unroll
    for (int df = 0; df < 8; ++df) o[df] = f32x4{0.f, 0.f, 0.f, 0.f};

    stage(c * 4 + 0);                              // tile 0 DMA overlaps inter

    // ---- inter: O += Q . H  (A=qf, B=HT rows; hi then lo) ----
    {
        const unsigned short* hbase_hi = HhiT + (size_t)(b * NC + c) * D_ * D_;
        const unsigned short* hbase_lo = HloT + (size_t)(b * NC + c) * D_ * D_;
        #pragma unroll
        for (int ks = 0; ks < 4; ++ks) {
            #pragma unroll
            for (int df = 0; df < 8; ++df) {
                const bf16x8 hh = *reinterpret_cast<const bf16x8*>(
                    hbase_hi + (size_t)(df * 16 + n) * D_ + 32 * ks + 8 * g);
                o[df] = __builtin_amdgcn_mfma_f32_16x16x32_bf16(qf[ks], hh, o[df], 0, 0, 0);
            }
        }
        #pragma unroll
        for (int ks = 0; ks < 4; ++ks) {
            #pragma unroll
            for (int df = 0; df < 8; ++df) {
                const bf16x8 hl = *reinterpret_cast<const bf16x8*>(
                    hbase_lo + (size_t)(df * 16 + n) * D_ + 32 * ks + 8 * g);
                o[df] = __builtin_amdgcn_mfma_f32_16x16x32_bf16(qf[ks], hl, o[df], 0, 0, 0);
            }
        }
    }

    // ---- intra: kt = 0..pp causal tiles within the chunk ----
    for (int kt = 0; kt <= pp; ++kt) {
        WAIT_VMCNT_0;                              // tile kt staged
        BARRIER;                                   // visible to all waves

        // E^T = K.Q^T (swapped): lane(g,n) holds E[t=tf*16+4g+rr][s=qg*64+wv*16+n]
        f32x4 e[4];
        #pragma unroll
        for (int tf = 0; tf < 4; ++tf) e[tf] = f32x4{0.f, 0.f, 0.f, 0.f};
        __builtin_amdgcn_s_setprio(1);
        #pragma unroll
        for (int tf = 0; tf < 4; ++tf) {
            #pragma unroll
            for (int ks = 0; ks < 4; ++ks) {
                const bf16x8 kf = *reinterpret_cast<const bf16x8*>(
                    &Kb[(tf * 16 + n) * 128 + (((4 * ks + g) ^ n) * 8)]);
                e[tf] = __builtin_amdgcn_mfma_f32_16x16x32_bf16(kf, qf[ks], e[tf], 0, 0, 0);
            }
        }
        __builtin_amdgcn_s_setprio(0);

        if (kt == pp) {                            // diagonal tile: causal mask
            int s_glob = qg * 64 + wv * 16 + n;
            #pragma unroll
            for (int tf = 0; tf < 4; ++tf)
                #pragma unroll
                for (int rr = 0; rr < 4; ++rr) {
                    int t_glob = (c * 4 + kt) * 64 + tf * 16 + 4 * g + rr;
                    if (t_glob > s_glob) e[tf][rr] = 0.f;
                }
        }

        // E -> P A-frags in-register (8 cvt_pk + 8 permlane swaps, r4-verified)
        bf16x8 pf[2];
        {
            unsigned u0[4], u1[4];
            #pragma unroll
            for (int tf = 0; tf < 4; ++tf) {
                asm("v_cvt_pk_bf16_f32 %0, %1, %2"
                    : "=v"(u0[tf]) : "v"(e[tf][0]), "v"(e[tf][1]));
                asm("v_cvt_pk_bf16_f32 %0, %1, %2"
                    : "=v"(u1[tf]) : "v"(e[tf][2]), "v"(e[tf][3]));
            }
            #pragma unroll
            for (int ks = 0; ks < 2; ++ks) {
                unsigned a0 = u0[2 * ks], a1 = u0[2 * ks + 1];
                unsigned b0 = u1[2 * ks], b1 = u1[2 * ks + 1];
                asm("v_permlane32_swap_b32 %0, %1" : "+v"(a0), "+v"(a1));
                asm("v_permlane32_swap_b32 %0, %1" : "+v"(b0), "+v"(b1));
                asm("v_permlane16_swap_b32 %0, %1" : "+v"(a0), "+v"(a1));
                asm("v_permlane16_swap_b32 %0, %1" : "+v"(b0), "+v"(b1));
                pf[ks] = __builtin_bit_cast(bf16x8, u32x4{a0, b0, a1, b1});
            }
        }

        // O += P.V
        __builtin_amdgcn_s_setprio(1);
        #pragma unroll
        for (int df = 0; df < 8; ++df) {
            #pragma unroll
            for (int ks = 0; ks < 2; ++ks) {
                const bf16x8 vf = *reinterpret_cast<const bf16x8*>(
                    &Vb[(df * 16 + n) * 64 + (((4 * ks + g) ^ (n & 7)) * 8)]);
                o[df] = __builtin_amdgcn_mfma_f32_16x16x32_bf16(pf[ks], vf, o[df], 0, 0, 0);
            }
        }
        __builtin_amdgcn_s_setprio(0);

        BARRIER;                                   // readers done before overwrite
        if (kt < pp) stage(c * 4 + kt + 1);
    }

    // ---- epilogue: exclusive rows -> plain stores ----
    #pragma unroll
    for (int df = 0; df < 8; ++df)
        #pragma unroll
        for (int rr = 0; rr < 4; ++rr) {
            int srow = qg * 64 + wv * 16 + 4 * g + rr;
            Out[((size_t)(b * S_ + srow)) * D_ + df * 16 + n] = o[df][rr];
        }
}

// ---------------------------------------------------------------------------
extern "C" void kernel_launch(void* const* d_in, const int* in_sizes, int n_in,
                              void* d_out, int out_size, void* d_ws, size_t ws_size,
                              hipStream_t stream) {
    const float* Q = (const float*)d_in[0];
    const float* K = (const float*)d_in[1];
    const float* V = (const float*)d_in[2];

    const size_t NE = (size_t)B_ * S_ * D_;       // 4.19M elems
    unsigned short* Qr = (unsigned short*)d_ws;
    unsigned short* Kr = Qr + NE;
    unsigned short* Kt = Kr + NE;
    unsigned short* Vt = Kt + NE;
    float*          P1 = (float*)(Vt + NE);                        // 8 MB f32
    unsigned short* HhiT = (unsigned short*)(P1 + (size_t)B_ * NC * D_ * D_);
    unsigned short* HloT = HhiT + (size_t)B_ * NC * D_ * D_;

    prep  <<<3072, 256, 0, stream>>>(Q, K, V, Qr, Kr, Kt, Vt);
    pass1 <<<B_ * NC, 256, 0, stream>>>(Kt, Vt, P1);
    prefix<<<512, 256, 0, stream>>>(P1, HhiT, HloT);
    pass2 <<<512, 256, 0, stream>>>(Qr, Kr, Vt, HhiT, HloT, (float*)d_out);
}

// Round 14
// 66.189 us; speedup vs baseline: 1.2769x; 1.2769x over previous
//
#include <hip/hip_runtime.h>
#include <hip/hip_bf16.h>

// Problem constants (B=8, S=4096, D=128 per reference setup_inputs)
#define B_ 8
#define S_ 4096
#define D_ 128
#define C_ 256                 // chunk length
#define NC 16                  // chunks per batch = S_/C_

typedef __attribute__((ext_vector_type(8))) short bf16x8;   // MFMA A/B frag (4 VGPRs)
typedef __attribute__((ext_vector_type(4))) float f32x4;    // 16x16 MFMA C/D frag
typedef __attribute__((ext_vector_type(4))) unsigned u32x4;

// f32 -> bf16 round-to-nearest-even
static __device__ __forceinline__ unsigned short f2bf(float x) {
    unsigned u = __float_as_uint(x);
    u += 0x7fffu + ((u >> 16) & 1u);
    return (unsigned short)(u >> 16);
}
static __device__ __forceinline__ float bf2f(unsigned short h) {
    return __uint_as_float(((unsigned)h) << 16);
}

// async global -> LDS, 16 bytes per lane (dest = wave-uniform base + lane*16)
typedef const __attribute__((address_space(1))) unsigned int* gas_ptr;
typedef __attribute__((address_space(3))) unsigned int* las_ptr;
static __device__ __forceinline__ void load_lds16(const unsigned short* g, unsigned short* l) {
    __builtin_amdgcn_global_load_lds((gas_ptr)(const void*)g, (las_ptr)(void*)l, 16, 0, 0);
}

#define WAIT_VMCNT_8 do { asm volatile("s_waitcnt vmcnt(8)" ::: "memory"); \
                          __builtin_amdgcn_sched_barrier(0); } while (0)
#define WAIT_VMCNT_0 do { asm volatile("s_waitcnt vmcnt(0)" ::: "memory"); \
                          __builtin_amdgcn_sched_barrier(0); } while (0)
#define BARRIER      do { __builtin_amdgcn_s_barrier(); \
                          __builtin_amdgcn_sched_barrier(0); } while (0)

// ---------------------------------------------------------------------------
// prep: [0,2048) RoPE Q,K -> Qr,Kr bf16 (natural [t][d])
//       [2048,2560) V transpose -> Vt bf16 [d][t]
//       [2560,3072) K transpose + RoPE -> Kt bf16 [d][t]
// (unchanged from round 13 — known-quantity cost)
// ---------------------------------------------------------------------------
__global__ __launch_bounds__(256) void prep(const float* __restrict__ Q,
                                            const float* __restrict__ K,
                                            const float* __restrict__ V,
                                            unsigned short* __restrict__ Qr,
                                            unsigned short* __restrict__ Kr,
                                            unsigned short* __restrict__ Kt,
                                            unsigned short* __restrict__ Vt) {
    __shared__ float smf[64 * 130];               // f32 tile; V branch reuses as ushort
    const int bid = blockIdx.x;
    const int tid = threadIdx.x;
    if (bid < 2048) {
        int e = bid * 256 + tid;                  // 0 .. 8*4096*16-1
        int t = e & 15;
        int s = (e >> 4) & (S_ - 1);
        int b = e >> 16;
        size_t base = ((size_t)(b * S_ + s)) * D_;
        int d0 = t * 4;
        float qa[4], qb[4], ka[4], kb[4];
        *(float4*)qa = *(const float4*)(Q + base + d0);
        *(float4*)qb = *(const float4*)(Q + base + d0 + 64);
        *(float4*)ka = *(const float4*)(K + base + d0);
        *(float4*)kb = *(const float4*)(K + base + d0 + 64);
        unsigned short ql[4], qh[4], kl[4], kh[4];
        #pragma unroll
        for (int jj = 0; jj < 4; ++jj) {
            float invf = exp2f(-0.20762050f * (float)(d0 + jj));  // 10000^{-(d0+jj)/64}
            float ang = (float)s * invf;
            float sn, cs;
            __sincosf(ang, &sn, &cs);
            ql[jj] = f2bf(qa[jj] * cs - qb[jj] * sn);
            qh[jj] = f2bf(qb[jj] * cs + qa[jj] * sn);
            kl[jj] = f2bf(ka[jj] * cs - kb[jj] * sn);
            kh[jj] = f2bf(kb[jj] * cs + ka[jj] * sn);
        }
        *reinterpret_cast<ushort4*>(Qr + base + d0)      = ushort4{ql[0], ql[1], ql[2], ql[3]};
        *reinterpret_cast<ushort4*>(Qr + base + d0 + 64) = ushort4{qh[0], qh[1], qh[2], qh[3]};
        *reinterpret_cast<ushort4*>(Kr + base + d0)      = ushort4{kl[0], kl[1], kl[2], kl[3]};
        *reinterpret_cast<ushort4*>(Kr + base + d0 + 64) = ushort4{kh[0], kh[1], kh[2], kh[3]};
    } else if (bid < 2560) {
        // V [B][S][D] f32 -> Vt [B][D][S] bf16
        unsigned short* tile = (unsigned short*)smf;
        int b2 = bid - 2048;                      // 0..511
        int b  = b2 >> 6;
        int t0 = (b2 & 63) * 64;
        #pragma unroll
        for (int it = 0; it < 32; ++it) {
            int e = it * 256 + tid;
            int tl = e >> 7, d = e & 127;
            tile[tl * 130 + d] = f2bf(V[((size_t)(b * S_ + t0 + tl)) * D_ + d]);
        }
        __syncthreads();
        #pragma unroll
        for (int it = 0; it < 32; ++it) {
            int e = it * 256 + tid;
            int d = e >> 6, tl = e & 63;
            Vt[((size_t)(b * D_ + d)) * S_ + t0 + tl] = tile[tl * 130 + d];
        }
    } else {
        // K [B][S][D] f32 -(RoPE)-> Kt [B][D][S] bf16
        int b2 = bid - 2560;                      // 0..511
        int b  = b2 >> 6;
        int t0 = (b2 & 63) * 64;
        #pragma unroll
        for (int it = 0; it < 32; ++it) {
            int e = it * 256 + tid;
            int tl = e >> 7, d = e & 127;
            smf[tl * 130 + d] = K[((size_t)(b * S_ + t0 + tl)) * D_ + d];
        }
        __syncthreads();
        #pragma unroll
        for (int it = 0; it < 32; ++it) {
            int e = it * 256 + tid;
            int d = e >> 6, tl = e & 63;
            float invf = exp2f(-0.20762050f * (float)(d & 63));
            float ang = (float)(t0 + tl) * invf;
            float sn, cs;
            __sincosf(ang, &sn, &cs);
            float x = smf[tl * 130 + d];
            float y = (d < 64) ? (x * cs - smf[tl * 130 + d + 64] * sn)
                               : (x * cs + smf[tl * 130 + d - 64] * sn);
            Kt[((size_t)(b * D_ + d)) * S_ + t0 + tl] = f2bf(y);
        }
    }
}

// ---------------------------------------------------------------------------
// pass1: half-chunk partials, TRANSPOSED: P1[b][c][half][dp][d] = V_h^T . K_h
//   (swapped MFMA operands: A=Vt rows dp, B=Kt rows d -> D[row=dp][col=d];
//    same products as K^T.V, stored transposed so prefix reads coalesce).
//   grid 256 = 8 b x 16 c x 2 halves (128 t each); wave w owns dp-rows
//   [32w,32w+32).
// ---------------------------------------------------------------------------
__global__ __launch_bounds__(256) void pass1(const unsigned short* __restrict__ Kt,
                                             const unsigned short* __restrict__ Vt,
                                             float* __restrict__ P1) {
    const int b    = blockIdx.x >> 5;
    const int c    = (blockIdx.x >> 1) & 15;
    const int half = blockIdx.x & 1;
    const int tid = threadIdx.x;
    const int w = tid >> 6;
    const int l = tid & 63;
    const int g = l >> 4;
    const int n = l & 15;

    f32x4 acc[2][8];
    #pragma unroll
    for (int dr = 0; dr < 2; ++dr)
        #pragma unroll
        for (int dc = 0; dc < 8; ++dc) acc[dr][dc] = f32x4{0.f, 0.f, 0.f, 0.f};

    const size_t tbase = (size_t)c * C_ + half * 128 + 8 * g;
    #pragma unroll
    for (int ki = 0; ki < 4; ++ki) {
        bf16x8 a[2];                               // A = Vt rows dp
        #pragma unroll
        for (int dr = 0; dr < 2; ++dr)
            a[dr] = *reinterpret_cast<const bf16x8*>(
                Vt + ((size_t)(b * D_ + w * 32 + dr * 16 + n)) * S_ + tbase + ki * 32);
        #pragma unroll
        for (int dc = 0; dc < 8; ++dc) {           // B = Kt rows d
            const bf16x8 bf = *reinterpret_cast<const bf16x8*>(
                Kt + ((size_t)(b * D_ + dc * 16 + n)) * S_ + tbase + ki * 32);
            acc[0][dc] = __builtin_amdgcn_mfma_f32_16x16x32_bf16(a[0], bf, acc[0][dc], 0, 0, 0);
            acc[1][dc] = __builtin_amdgcn_mfma_f32_16x16x32_bf16(a[1], bf, acc[1][dc], 0, 0, 0);
        }
    }

    float* out = P1 + (size_t)((b * NC + c) * 2 + half) * D_ * D_;
    #pragma unroll
    for (int dr = 0; dr < 2; ++dr)
        #pragma unroll
        for (int dc = 0; dc < 8; ++dc)
            #pragma unroll
            for (int rr = 0; rr < 4; ++rr)
                out[(size_t)(w * 32 + dr * 16 + 4 * g + rr) * D_ + dc * 16 + n]
                    = acc[dr][dc][rr];
}

// ---------------------------------------------------------------------------
// prefix: exclusive prefix over 32 half-chunk partials; emit H^T bf16 hi+lo.
//   thread -> (b,dp,d) with d = gid&127 -> ALL reads/writes coalesced.
//   HT layout [b][c][dp][d].
// ---------------------------------------------------------------------------
__global__ __launch_bounds__(256) void prefix(const float* __restrict__ P1,
                                              unsigned short* __restrict__ HhiT,
                                              unsigned short* __restrict__ HloT) {
    int gid = blockIdx.x * 256 + threadIdx.x;     // 0 .. 131071
    int d  = gid & 127;
    int dp = (gid >> 7) & 127;
    int b  = gid >> 14;
    float run = 0.f;
    #pragma unroll
    for (int c = 0; c < NC; ++c) {
        unsigned short hi = f2bf(run);
        float rem = run - bf2f(hi);
        size_t idx = ((size_t)(b * NC + c) * D_ + dp) * D_ + d;
        HhiT[idx] = hi;
        HloT[idx] = f2bf(rem);
        size_t p = ((size_t)((b * NC + c) * 2) * D_ + dp) * D_ + d;
        run += P1[p];
        run += P1[p + (size_t)D_ * D_];
    }
}

// ---------------------------------------------------------------------------
// pass2: O_c = Qr_c . H_c (inter, hi+lo)  +  causal(Qr_c.Kr_c^T).V_c (intra).
//   512 blocks = 4 pp-groups x 128 (b,c); pp dispatch perm {3,2,0,1} so
//   co-resident pairs (3,0),(2,1) balance. 4 waves x 16 q-rows.
//   Intra: K/V DOUBLE-buffered (64KB), r6/r8 counted-vmcnt skeleton:
//     prologue stage(t0[,t1]) | inter | loop: vmcnt(8|0)+bar | compute |
//     bar | stage(t_{kt+2}). No atomics; plain stores.
// MFMA 16x16x32 bf16 layouts (verified rounds 1-10):
//   A: lane l holds A[row=l&15][k=8*(l>>4)+j]; B: B[k=8*(l>>4)+j][col=l&15]
//   C/D: lane,reg holds D[row=4*(l>>4)+reg][col=l&15]
// ---------------------------------------------------------------------------
__global__ __launch_bounds__(256, 2) void pass2(const unsigned short* __restrict__ Qr,
                                                const unsigned short* __restrict__ Kr,
                                                const unsigned short* __restrict__ Vt,
                                                const unsigned short* __restrict__ HhiT,
                                                const unsigned short* __restrict__ HloT,
                                                float* __restrict__ Out) {
    __shared__ unsigned short Kb[2][64 * 128];    // [t][d] swizzled chunks, 2x16KB
    __shared__ unsigned short Vb[2][128 * 64];    // [d][t] swizzled chunks, 2x16KB

    const int bid = blockIdx.x;
    const int ppmap[4] = {3, 2, 0, 1};
    const int pp = ppmap[bid >> 7];               // sub-block (q-64-tile within chunk)
    const int r2 = bid & 127;
    const int b  = r2 & 7;
    const int c  = r2 >> 3;                       // chunk 0..15
    const int qg = c * 4 + pp;                    // global 64-row q-tile index
    const int c4 = c * 4;

    const int tid = threadIdx.x;
    const int wv = tid >> 6;
    const int l  = tid & 63;
    const int g  = l >> 4;
    const int n  = l & 15;

    // K LDS chunk (t,cc) <- global chunk (t, cc^(t&15)); V chunk (d,cc) <- cc^(d&7)
    auto stage = [&](int bufs, int tg) {
        const unsigned short* kbase = Kr + ((size_t)(b * S_ + tg * 64)) * D_;
        #pragma unroll
        for (int i = 0; i < 4; ++i) {
            int ci = i * 256 + tid;
            int t = ci >> 4, cc = ci & 15;
            load_lds16(kbase + t * D_ + ((cc ^ (t & 15)) * 8), &Kb[bufs][ci * 8]);
        }
        const unsigned short* vbase = Vt + (size_t)b * D_ * S_ + (size_t)tg * 64;
        #pragma unroll
        for (int i = 0; i < 4; ++i) {
            int ci = i * 256 + tid;
            int d = ci >> 3, cc = ci & 7;
            load_lds16(vbase + (size_t)d * S_ + ((cc ^ (d & 7)) * 8), &Vb[bufs][ci * 8]);
        }
    };

    // hoist Q fragments (16 rows/wave)
    bf16x8 qf[4];
    {
        const unsigned short* qp =
            Qr + ((size_t)(b * S_ + qg * 64 + wv * 16 + n)) * D_ + 8 * g;
        #pragma unroll
        for (int ks = 0; ks < 4; ++ks)
            qf[ks] = *reinterpret_cast<const bf16x8*>(qp + ks * 32);
    }

    f32x4 o[8];
    #pragma unroll
    for (int df = 0; df < 8; ++df) o[df] = f32x4{0.f, 0.f, 0.f, 0.f};

    stage(0, c4);                                  // tile 0 (8 vm entries)
    if (pp >= 1) stage(1, c4 + 1);                 // tile 1 (8 more)

    // ---- inter: O += Q . H  (A=qf, B=HT rows; hi then lo); DMAs fly under it ----
    {
        const unsigned short* hbase_hi = HhiT + (size_t)(b * NC + c) * D_ * D_;
        const unsigned short* hbase_lo = HloT + (size_t)(b * NC + c) * D_ * D_;
        #pragma unroll
        for (int ks = 0; ks < 4; ++ks) {
            #pragma unroll
            for (int df = 0; df < 8; ++df) {
                const bf16x8 hh = *reinterpret_cast<const bf16x8*>(
                    hbase_hi + (size_t)(df * 16 + n) * D_ + 32 * ks + 8 * g);
                o[df] = __builtin_amdgcn_mfma_f32_16x16x32_bf16(qf[ks], hh, o[df], 0, 0, 0);
            }
        }
        #pragma unroll
        for (int ks = 0; ks < 4; ++ks) {
            #pragma unroll
            for (int df = 0; df < 8; ++df) {
                const bf16x8 hl = *reinterpret_cast<const bf16x8*>(
                    hbase_lo + (size_t)(df * 16 + n) * D_ + 32 * ks + 8 * g);
                o[df] = __builtin_amdgcn_mfma_f32_16x16x32_bf16(qf[ks], hl, o[df], 0, 0, 0);
            }
        }
    }

    // ---- intra: kt = 0..pp causal tiles, double-buffered counted-vmcnt ----
    for (int kt = 0; kt <= pp; ++kt) {
        if (kt < pp) { WAIT_VMCNT_8; }             // tile kt landed; kt+1 in flight
        else         { WAIT_VMCNT_0; }
        BARRIER;

        const int bufc = kt & 1;

        // E^T = K.Q^T (swapped): lane(g,n) holds E[t=tf*16+4g+rr][s=qg*64+wv*16+n]
        f32x4 e[4];
        #pragma unroll
        for (int tf = 0; tf < 4; ++tf) e[tf] = f32x4{0.f, 0.f, 0.f, 0.f};
        __builtin_amdgcn_s_setprio(1);
        #pragma unroll
        for (int tf = 0; tf < 4; ++tf) {
            #pragma unroll
            for (int ks = 0; ks < 4; ++ks) {
                const bf16x8 kf = *reinterpret_cast<const bf16x8*>(
                    &Kb[bufc][(tf * 16 + n) * 128 + (((4 * ks + g) ^ n) * 8)]);
                e[tf] = __builtin_amdgcn_mfma_f32_16x16x32_bf16(kf, qf[ks], e[tf], 0, 0, 0);
            }
        }
        __builtin_amdgcn_s_setprio(0);

        if (kt == pp) {                            // diagonal tile: causal mask
            int s_glob = qg * 64 + wv * 16 + n;
            #pragma unroll
            for (int tf = 0; tf < 4; ++tf)
                #pragma unroll
                for (int rr = 0; rr < 4; ++rr) {
                    int t_glob = (c4 + kt) * 64 + tf * 16 + 4 * g + rr;
                    if (t_glob > s_glob) e[tf][rr] = 0.f;
                }
        }

        // E -> P A-frags in-register (8 cvt_pk + 8 permlane swaps, r4-verified)
        bf16x8 pf[2];
        {
            unsigned u0[4], u1[4];
            #pragma unroll
            for (int tf = 0; tf < 4; ++tf) {
                asm("v_cvt_pk_bf16_f32 %0, %1, %2"
                    : "=v"(u0[tf]) : "v"(e[tf][0]), "v"(e[tf][1]));
                asm("v_cvt_pk_bf16_f32 %0, %1, %2"
                    : "=v"(u1[tf]) : "v"(e[tf][2]), "v"(e[tf][3]));
            }
            #pragma unroll
            for (int ks = 0; ks < 2; ++ks) {
                unsigned a0 = u0[2 * ks], a1 = u0[2 * ks + 1];
                unsigned b0 = u1[2 * ks], b1 = u1[2 * ks + 1];
                asm("v_permlane32_swap_b32 %0, %1" : "+v"(a0), "+v"(a1));
                asm("v_permlane32_swap_b32 %0, %1" : "+v"(b0), "+v"(b1));
                asm("v_permlane16_swap_b32 %0, %1" : "+v"(a0), "+v"(a1));
                asm("v_permlane16_swap_b32 %0, %1" : "+v"(b0), "+v"(b1));
                pf[ks] = __builtin_bit_cast(bf16x8, u32x4{a0, b0, a1, b1});
            }
        }

        // O += P.V
        __builtin_amdgcn_s_setprio(1);
        #pragma unroll
        for (int df = 0; df < 8; ++df) {
            #pragma unroll
            for (int ks = 0; ks < 2; ++ks) {
                const bf16x8 vf = *reinterpret_cast<const bf16x8*>(
                    &Vb[bufc][(df * 16 + n) * 64 + (((4 * ks + g) ^ (n & 7)) * 8)]);
                o[df] = __builtin_amdgcn_mfma_f32_16x16x32_bf16(pf[ks], vf, o[df], 0, 0, 0);
            }
        }
        __builtin_amdgcn_s_setprio(0);

        BARRIER;                                   // all waves done reading bufc

        if (kt + 2 <= pp) stage(bufc, c4 + kt + 2);
    }

    // ---- epilogue: exclusive rows -> plain stores ----
    #pragma unroll
    for (int df = 0; df < 8; ++df)
        #pragma unroll
        for (int rr = 0; rr < 4; ++rr) {
            int srow = qg * 64 + wv * 16 + 4 * g + rr;
            Out[((size_t)(b * S_ + srow)) * D_ + df * 16 + n] = o[df][rr];
        }
}

// ---------------------------------------------------------------------------
extern "C" void kernel_launch(void* const* d_in, const int* in_sizes, int n_in,
                              void* d_out, int out_size, void* d_ws, size_t ws_size,
                              hipStream_t stream) {
    const float* Q = (const float*)d_in[0];
    const float* K = (const float*)d_in[1];
    const float* V = (const float*)d_in[2];

    const size_t NE = (size_t)B_ * S_ * D_;       // 4.19M elems
    unsigned short* Qr = (unsigned short*)d_ws;
    unsigned short* Kr = Qr + NE;
    unsigned short* Kt = Kr + NE;
    unsigned short* Vt = Kt + NE;
    float*          P1 = (float*)(Vt + NE);                        // 32 MB f32
    unsigned short* HhiT = (unsigned short*)(P1 + (size_t)B_ * NC * 2 * D_ * D_);
    unsigned short* HloT = HhiT + (size_t)B_ * NC * D_ * D_;

    prep  <<<3072, 256, 0, stream>>>(Q, K, V, Qr, Kr, Kt, Vt);
    pass1 <<<256, 256, 0, stream>>>(Kt, Vt, P1);
    prefix<<<512, 256, 0, stream>>>(P1, HhiT, HloT);
    pass2 <<<512, 256, 0, stream>>>(Qr, Kr, Vt, HhiT, HloT, (float*)d_out);
}

// Round 15
// 57.184 us; speedup vs baseline: 1.4780x; 1.1575x over previous
//
#include <hip/hip_runtime.h>
#include <hip/hip_bf16.h>

// Problem constants (B=8, S=4096, D=128 per reference setup_inputs)
#define B_ 8
#define S_ 4096
#define D_ 128
#define C_ 256                 // chunk length
#define NC 16                  // chunks per batch = S_/C_

typedef __attribute__((ext_vector_type(8))) short bf16x8;   // MFMA A/B frag (4 VGPRs)
typedef __attribute__((ext_vector_type(4))) float f32x4;    // 16x16 MFMA C/D frag
typedef __attribute__((ext_vector_type(4))) unsigned u32x4;

// f32 -> bf16 round-to-nearest-even
static __device__ __forceinline__ unsigned short f2bf(float x) {
    unsigned u = __float_as_uint(x);
    u += 0x7fffu + ((u >> 16) & 1u);
    return (unsigned short)(u >> 16);
}

// async global -> LDS, 16 bytes per lane (dest = wave-uniform base + lane*16)
typedef const __attribute__((address_space(1))) unsigned int* gas_ptr;
typedef __attribute__((address_space(3))) unsigned int* las_ptr;
static __device__ __forceinline__ void load_lds16(const unsigned short* g, unsigned short* l) {
    __builtin_amdgcn_global_load_lds((gas_ptr)(const void*)g, (las_ptr)(void*)l, 16, 0, 0);
}

#define WAIT_VMCNT_8 do { asm volatile("s_waitcnt vmcnt(8)" ::: "memory"); \
                          __builtin_amdgcn_sched_barrier(0); } while (0)
#define WAIT_VMCNT_0 do { asm volatile("s_waitcnt vmcnt(0)" ::: "memory"); \
                          __builtin_amdgcn_sched_barrier(0); } while (0)
#define BARRIER      do { __builtin_amdgcn_s_barrier(); \
                          __builtin_amdgcn_sched_barrier(0); } while (0)

// ---------------------------------------------------------------------------
// prep: [0,512)    V [B][S][D] f32 -> Vt [B][D][S] bf16
//       [512,1024) K f32 -(RoPE once)-> Kr [t][d] AND Kt [d][t] bf16
// (Q is NOT materialized — pass2 RoPEs it in-register.)
// ---------------------------------------------------------------------------
__global__ __launch_bounds__(256) void prep(const float* __restrict__ K,
                                            const float* __restrict__ V,
                                            unsigned short* __restrict__ Kr,
                                            unsigned short* __restrict__ Kt,
                                            unsigned short* __restrict__ Vt) {
    __shared__ float          smf[64 * 130];      // f32 stage (K branch)
    __shared__ unsigned short smh[64 * 130];      // bf16 stage (both branches)
    const int bid = blockIdx.x;
    const int tid = threadIdx.x;
    if (bid < 512) {
        // ---- V transpose ----
        int b  = bid >> 6;
        int t0 = (bid & 63) * 64;
        #pragma unroll
        for (int it = 0; it < 32; ++it) {
            int e = it * 256 + tid;
            int tl = e >> 7, d = e & 127;
            smh[tl * 130 + d] = f2bf(V[((size_t)(b * S_ + t0 + tl)) * D_ + d]);
        }
        __syncthreads();
        #pragma unroll
        for (int it = 0; it < 32; ++it) {
            int e = it * 256 + tid;
            int d = e >> 6, tl = e & 63;
            Vt[((size_t)(b * D_ + d)) * S_ + t0 + tl] = smh[tl * 130 + d];
        }
    } else {
        // ---- K: one read, RoPE once, two writes ----
        int b2 = bid - 512;                       // 0..511
        int b  = b2 >> 6;
        int t0 = (b2 & 63) * 64;
        #pragma unroll
        for (int it = 0; it < 32; ++it) {
            int e = it * 256 + tid;
            int tl = e >> 7, d = e & 127;
            smf[tl * 130 + d] = K[((size_t)(b * S_ + t0 + tl)) * D_ + d];
        }
        __syncthreads();
        #pragma unroll
        for (int it = 0; it < 32; ++it) {         // (tl,d): coalesced Kr write
            int e = it * 256 + tid;
            int tl = e >> 7, d = e & 127;
            float invf = exp2f(-0.20762050f * (float)(d & 63));
            float ang = (float)(t0 + tl) * invf;
            float sn, cs;
            __sincosf(ang, &sn, &cs);
            float x = smf[tl * 130 + d];
            float y = (d < 64) ? (x * cs - smf[tl * 130 + d + 64] * sn)
                               : (x * cs + smf[tl * 130 + d - 64] * sn);
            unsigned short h = f2bf(y);
            Kr[((size_t)(b * S_ + t0 + tl)) * D_ + d] = h;
            smh[tl * 130 + d] = h;
        }
        __syncthreads();
        #pragma unroll
        for (int it = 0; it < 32; ++it) {         // (d,tl): coalesced Kt write
            int e = it * 256 + tid;
            int d = e >> 6, tl = e & 63;
            Kt[((size_t)(b * D_ + d)) * S_ + t0 + tl] = smh[tl * 130 + d];
        }
    }
}

// ---------------------------------------------------------------------------
// pass1: per-chunk partials G[b][c][dp][d] = sum_t V[t][dp] K[t][d]  (f32).
//   grid 256 = 8 b x 16 c x 2 dp-slabs (64 rows); wave w owns dp rows
//   [slab*64 + w*16, +16). A = Vt row dp, B = Kt row d. 64 MFMAs/wave.
// ---------------------------------------------------------------------------
__global__ __launch_bounds__(256) void pass1(const unsigned short* __restrict__ Kt,
                                             const unsigned short* __restrict__ Vt,
                                             float* __restrict__ P1) {
    const int b    = blockIdx.x >> 5;
    const int c    = (blockIdx.x >> 1) & 15;
    const int slab = blockIdx.x & 1;
    const int tid = threadIdx.x;
    const int w = tid >> 6;
    const int l = tid & 63;
    const int g = l >> 4;
    const int n = l & 15;

    f32x4 acc[8];
    #pragma unroll
    for (int dc = 0; dc < 8; ++dc) acc[dc] = f32x4{0.f, 0.f, 0.f, 0.f};

    const size_t tbase = (size_t)c * C_ + 8 * g;
    const unsigned short* arow =
        Vt + ((size_t)(b * D_ + slab * 64 + w * 16 + n)) * S_ + tbase;
    #pragma unroll
    for (int ki = 0; ki < 8; ++ki) {
        const bf16x8 a = *reinterpret_cast<const bf16x8*>(arow + ki * 32);
        #pragma unroll
        for (int dc = 0; dc < 8; ++dc) {
            const bf16x8 bf = *reinterpret_cast<const bf16x8*>(
                Kt + ((size_t)(b * D_ + dc * 16 + n)) * S_ + tbase + ki * 32);
            acc[dc] = __builtin_amdgcn_mfma_f32_16x16x32_bf16(a, bf, acc[dc], 0, 0, 0);
        }
    }

    float* out = P1 + (size_t)(b * NC + c) * D_ * D_;
    #pragma unroll
    for (int dc = 0; dc < 8; ++dc)
        #pragma unroll
        for (int rr = 0; rr < 4; ++rr)
            out[(size_t)(slab * 64 + w * 16 + 4 * g + rr) * D_ + dc * 16 + n]
                = acc[dc][rr];
}

// ---------------------------------------------------------------------------
// prefix: exclusive prefix over chunk partials; emit G^prefix as single bf16.
//   thread -> (b,dp,d), d = gid&127 -> all reads/writes coalesced.
// ---------------------------------------------------------------------------
__global__ __launch_bounds__(256) void prefix(const float* __restrict__ P1,
                                              unsigned short* __restrict__ Hhi) {
    int gid = blockIdx.x * 256 + threadIdx.x;     // 0 .. 131071
    int d  = gid & 127;
    int dp = (gid >> 7) & 127;
    int b  = gid >> 14;
    float run = 0.f;
    #pragma unroll
    for (int c = 0; c < NC; ++c) {
        size_t idx = ((size_t)(b * NC + c) * D_ + dp) * D_ + d;
        Hhi[idx] = f2bf(run);
        run += P1[idx];
    }
}

// ---------------------------------------------------------------------------
// pass2: O_c = Qr_c . H_c (inter)  +  causal(Qr_c.Kr_c^T).V_c (intra).
//   Q is RoPE'd IN-REGISTER from f32 (pair (d,d+64) = same lane, ks and ks+2).
//   512 blocks = 4 pp-groups (perm {3,2,0,1}) x 128 (b,c); 4 waves x 16 rows.
//   Intra: K/V double-buffered (64KB), r14 counted-vmcnt skeleton (proven).
// MFMA 16x16x32 bf16 layouts (verified rounds 1-10):
//   A: lane l holds A[row=l&15][k=8*(l>>4)+j]; B: B[k=8*(l>>4)+j][col=l&15]
//   C/D: lane,reg holds D[row=4*(l>>4)+reg][col=l&15]
// ---------------------------------------------------------------------------
__global__ __launch_bounds__(256, 2) void pass2(const float* __restrict__ Q,
                                                const unsigned short* __restrict__ Kr,
                                                const unsigned short* __restrict__ Vt,
                                                const unsigned short* __restrict__ Hhi,
                                                float* __restrict__ Out) {
    __shared__ unsigned short Kb[2][64 * 128];    // [t][d] swizzled chunks, 2x16KB
    __shared__ unsigned short Vb[2][128 * 64];    // [d][t] swizzled chunks, 2x16KB

    const int bid = blockIdx.x;
    const int ppmap[4] = {3, 2, 0, 1};
    const int pp = ppmap[bid >> 7];               // q-64-tile within chunk
    const int r2 = bid & 127;
    const int b  = r2 & 7;
    const int c  = r2 >> 3;                       // chunk 0..15
    const int qg = c * 4 + pp;
    const int c4 = c * 4;

    const int tid = threadIdx.x;
    const int wv = tid >> 6;
    const int l  = tid & 63;
    const int g  = l >> 4;
    const int n  = l & 15;

    // ---- hoist Q with in-register RoPE: lane holds Q[s][d=32ks+8g+j] ----
    bf16x8 qf[4];
    {
        const int s = qg * 64 + wv * 16 + n;
        const float* qp = Q + ((size_t)(b * S_ + s)) * D_ + 8 * g;
        float qv[4][8];
        #pragma unroll
        for (int ks = 0; ks < 4; ++ks) {
            *reinterpret_cast<float4*>(&qv[ks][0]) =
                *reinterpret_cast<const float4*>(qp + 32 * ks);
            *reinterpret_cast<float4*>(&qv[ks][4]) =
                *reinterpret_cast<const float4*>(qp + 32 * ks + 4);
        }
        unsigned short qb[4][8];
        #pragma unroll
        for (int hf = 0; hf < 2; ++hf)
            #pragma unroll
            for (int j = 0; j < 8; ++j) {
                int dm = 32 * hf + 8 * g + j;     // d mod 64
                float invf = exp2f(-0.20762050f * (float)dm);
                float ang = (float)s * invf;
                float sn, cs;
                __sincosf(ang, &sn, &cs);
                qb[hf][j]     = f2bf(qv[hf][j] * cs - qv[hf + 2][j] * sn);
                qb[hf + 2][j] = f2bf(qv[hf + 2][j] * cs + qv[hf][j] * sn);
            }
        #pragma unroll
        for (int ks = 0; ks < 4; ++ks) {
            bf16x8 f;
            #pragma unroll
            for (int j = 0; j < 8; ++j) f[j] = (short)qb[ks][j];
            qf[ks] = f;
        }
    }

    // K LDS chunk (t,cc) <- global chunk (t, cc^(t&15)); V chunk (d,cc) <- cc^(d&7)
    auto stage = [&](int bufs, int tg) {
        const unsigned short* kbase = Kr + ((size_t)(b * S_ + tg * 64)) * D_;
        #pragma unroll
        for (int i = 0; i < 4; ++i) {
            int ci = i * 256 + tid;
            int t = ci >> 4, cc = ci & 15;
            load_lds16(kbase + t * D_ + ((cc ^ (t & 15)) * 8), &Kb[bufs][ci * 8]);
        }
        const unsigned short* vbase = Vt + (size_t)b * D_ * S_ + (size_t)tg * 64;
        #pragma unroll
        for (int i = 0; i < 4; ++i) {
            int ci = i * 256 + tid;
            int d = ci >> 3, cc = ci & 7;
            load_lds16(vbase + (size_t)d * S_ + ((cc ^ (d & 7)) * 8), &Vb[bufs][ci * 8]);
        }
    };

    f32x4 o[8];
    #pragma unroll
    for (int df = 0; df < 8; ++df) o[df] = f32x4{0.f, 0.f, 0.f, 0.f};

    stage(0, c4);                                  // tile 0 (8 vm entries)
    if (pp >= 1) stage(1, c4 + 1);                 // tile 1 (8 more)

    // ---- inter: O += Q . H (single bf16 H); DMAs fly underneath ----
    {
        const unsigned short* hbase = Hhi + (size_t)(b * NC + c) * D_ * D_;
        #pragma unroll
        for (int ks = 0; ks < 4; ++ks) {
            #pragma unroll
            for (int df = 0; df < 8; ++df) {
                const bf16x8 hh = *reinterpret_cast<const bf16x8*>(
                    hbase + (size_t)(df * 16 + n) * D_ + 32 * ks + 8 * g);
                o[df] = __builtin_amdgcn_mfma_f32_16x16x32_bf16(qf[ks], hh, o[df], 0, 0, 0);
            }
        }
    }

    // ---- intra: kt = 0..pp causal tiles, double-buffered counted-vmcnt ----
    for (int kt = 0; kt <= pp; ++kt) {
        if (kt < pp) { WAIT_VMCNT_8; }             // tile kt landed; kt+1 in flight
        else         { WAIT_VMCNT_0; }
        BARRIER;

        const int bufc = kt & 1;

        // E^T = K.Q^T (swapped): lane(g,n) holds E[t=tf*16+4g+rr][s=qg*64+wv*16+n]
        f32x4 e[4];
        #pragma unroll
        for (int tf = 0; tf < 4; ++tf) e[tf] = f32x4{0.f, 0.f, 0.f, 0.f};
        __builtin_amdgcn_s_setprio(1);
        #pragma unroll
        for (int tf = 0; tf < 4; ++tf) {
            #pragma unroll
            for (int ks = 0; ks < 4; ++ks) {
                const bf16x8 kf = *reinterpret_cast<const bf16x8*>(
                    &Kb[bufc][(tf * 16 + n) * 128 + (((4 * ks + g) ^ n) * 8)]);
                e[tf] = __builtin_amdgcn_mfma_f32_16x16x32_bf16(kf, qf[ks], e[tf], 0, 0, 0);
            }
        }
        __builtin_amdgcn_s_setprio(0);

        if (kt == pp) {                            // diagonal tile: causal mask
            int s_glob = qg * 64 + wv * 16 + n;
            #pragma unroll
            for (int tf = 0; tf < 4; ++tf)
                #pragma unroll
                for (int rr = 0; rr < 4; ++rr) {
                    int t_glob = (c4 + kt) * 64 + tf * 16 + 4 * g + rr;
                    if (t_glob > s_glob) e[tf][rr] = 0.f;
                }
        }

        // E -> P A-frags in-register (8 cvt_pk + 8 permlane swaps, r4-verified)
        bf16x8 pf[2];
        {
            unsigned u0[4], u1[4];
            #pragma unroll
            for (int tf = 0; tf < 4; ++tf) {
                asm("v_cvt_pk_bf16_f32 %0, %1, %2"
                    : "=v"(u0[tf]) : "v"(e[tf][0]), "v"(e[tf][1]));
                asm("v_cvt_pk_bf16_f32 %0, %1, %2"
                    : "=v"(u1[tf]) : "v"(e[tf][2]), "v"(e[tf][3]));
            }
            #pragma unroll
            for (int ks = 0; ks < 2; ++ks) {
                unsigned a0 = u0[2 * ks], a1 = u0[2 * ks + 1];
                unsigned b0 = u1[2 * ks], b1 = u1[2 * ks + 1];
                asm("v_permlane32_swap_b32 %0, %1" : "+v"(a0), "+v"(a1));
                asm("v_permlane32_swap_b32 %0, %1" : "+v"(b0), "+v"(b1));
                asm("v_permlane16_swap_b32 %0, %1" : "+v"(a0), "+v"(a1));
                asm("v_permlane16_swap_b32 %0, %1" : "+v"(b0), "+v"(b1));
                pf[ks] = __builtin_bit_cast(bf16x8, u32x4{a0, b0, a1, b1});
            }
        }

        // O += P.V
        __builtin_amdgcn_s_setprio(1);
        #pragma unroll
        for (int df = 0; df < 8; ++df) {
            #pragma unroll
            for (int ks = 0; ks < 2; ++ks) {
                const bf16x8 vf = *reinterpret_cast<const bf16x8*>(
                    &Vb[bufc][(df * 16 + n) * 64 + (((4 * ks + g) ^ (n & 7)) * 8)]);
                o[df] = __builtin_amdgcn_mfma_f32_16x16x32_bf16(pf[ks], vf, o[df], 0, 0, 0);
            }
        }
        __builtin_amdgcn_s_setprio(0);

        BARRIER;                                   // all waves done reading bufc

        if (kt + 2 <= pp) stage(bufc, c4 + kt + 2);
    }

    // ---- epilogue: exclusive rows -> plain stores ----
    #pragma unroll
    for (int df = 0; df < 8; ++df)
        #pragma unroll
        for (int rr = 0; rr < 4; ++rr) {
            int srow = qg * 64 + wv * 16 + 4 * g + rr;
            Out[((size_t)(b * S_ + srow)) * D_ + df * 16 + n] = o[df][rr];
        }
}

// ---------------------------------------------------------------------------
extern "C" void kernel_launch(void* const* d_in, const int* in_sizes, int n_in,
                              void* d_out, int out_size, void* d_ws, size_t ws_size,
                              hipStream_t stream) {
    const float* Q = (const float*)d_in[0];
    const float* K = (const float*)d_in[1];
    const float* V = (const float*)d_in[2];

    const size_t NE = (size_t)B_ * S_ * D_;       // 4.19M elems
    unsigned short* Kr = (unsigned short*)d_ws;                    // 8 MB
    unsigned short* Kt = Kr + NE;                                  // 8 MB
    unsigned short* Vt = Kt + NE;                                  // 8 MB
    float*          P1 = (float*)(Vt + NE);                        // 8 MB f32
    unsigned short* Hhi = (unsigned short*)(P1 + (size_t)B_ * NC * D_ * D_);  // 4 MB

    prep  <<<1024, 256, 0, stream>>>(K, V, Kr, Kt, Vt);
    pass1 <<<256, 256, 0, stream>>>(Kt, Vt, P1);
    prefix<<<512, 256, 0, stream>>>(P1, Hhi);
    pass2 <<<512, 256, 0, stream>>>(Q, Kr, Vt, Hhi, (float*)d_out);
}

// Round 16
// 40.603 us; speedup vs baseline: 2.0816x; 1.4084x over previous
//
#include <hip/hip_runtime.h>
#include <hip/hip_bf16.h>

// Problem constants (B=8, S=4096, D=128 per reference setup_inputs)
#define B_ 8
#define S_ 4096
#define D_ 128
#define C_ 256                 // chunk length
#define NC 16                  // chunks per batch = S_/C_

typedef __attribute__((ext_vector_type(8))) short bf16x8;   // MFMA A/B frag (4 VGPRs)
typedef __attribute__((ext_vector_type(4))) float f32x4;    // 16x16 MFMA C/D frag
typedef __attribute__((ext_vector_type(4))) unsigned u32x4;

// f32 -> bf16 round-to-nearest-even
static __device__ __forceinline__ unsigned short f2bf(float x) {
    unsigned u = __float_as_uint(x);
    u += 0x7fffu + ((u >> 16) & 1u);
    return (unsigned short)(u >> 16);
}

// async global -> LDS, 16 bytes per lane (dest = wave-uniform base + lane*16)
typedef const __attribute__((address_space(1))) unsigned int* gas_ptr;
typedef __attribute__((address_space(3))) unsigned int* las_ptr;
static __device__ __forceinline__ void load_lds16(const unsigned short* g, unsigned short* l) {
    __builtin_amdgcn_global_load_lds((gas_ptr)(const void*)g, (las_ptr)(void*)l, 16, 0, 0);
}

#define WAIT_VMCNT_8 do { asm volatile("s_waitcnt vmcnt(8)" ::: "memory"); \
                          __builtin_amdgcn_sched_barrier(0); } while (0)
#define WAIT_VMCNT_0 do { asm volatile("s_waitcnt vmcnt(0)" ::: "memory"); \
                          __builtin_amdgcn_sched_barrier(0); } while (0)
#define BARRIER      do { __builtin_amdgcn_s_barrier(); \
                          __builtin_amdgcn_sched_barrier(0); } while (0)

// ---------------------------------------------------------------------------
// fusedA: per (b, chunk, t-half of 128):
//   read K,V f32 half-chunk; RoPE K in-register; write Kr natural;
//   scatter transposed bf16 K/V into XOR-swizzled LDS (cc ^ (row&15), the
//   r6-certified zero-conflict pattern); write Vt [B][D][S] from LDS;
//   compute G half-partial P1[b][c][half][dp][d] = sum_t V[t][dp] K[t][d]
//   via MFMA straight from LDS. Kt never touches HBM.
// MFMA 16x16x32 bf16 layouts (verified rounds 1-15):
//   A: lane l holds A[row=l&15][k=8*(l>>4)+j]; B: B[k=8*(l>>4)+j][col=l&15]
//   C/D: lane,reg holds D[row=4*(l>>4)+reg][col=l&15]
// ---------------------------------------------------------------------------
__global__ __launch_bounds__(256, 2) void fusedA(const float* __restrict__ K,
                                                 const float* __restrict__ V,
                                                 unsigned short* __restrict__ Kr,
                                                 unsigned short* __restrict__ Vt,
                                                 float* __restrict__ P1) {
    __shared__ unsigned short Klds[128 * 128];    // [d][t-half] swizzled chunks, 32KB
    __shared__ unsigned short Vlds[128 * 128];    // same, 32KB

    const int b    = blockIdx.x >> 5;
    const int c    = (blockIdx.x >> 1) & 15;
    const int half = blockIdx.x & 1;
    const int tid  = threadIdx.x;
    const int t0   = c * C_ + half * 128;         // global t base of this half

    // ---- load f32, RoPE K, write Kr, scatter transposed bf16 to LDS ----
    #pragma unroll
    for (int it = 0; it < 8; ++it) {
        int e  = it * 256 + tid;
        int tl = e >> 4;                          // 0..127 local t
        int d0 = (e & 15) * 4;                    // 0..60 (pairs with d0+64)
        size_t gbase = ((size_t)(b * S_ + t0 + tl)) * D_;
        float ka[4], kb[4], va[4], vb[4];
        *(float4*)ka = *(const float4*)(K + gbase + d0);
        *(float4*)kb = *(const float4*)(K + gbase + d0 + 64);
        *(float4*)va = *(const float4*)(V + gbase + d0);
        *(float4*)vb = *(const float4*)(V + gbase + d0 + 64);
        unsigned short kl[4], kh[4];
        #pragma unroll
        for (int jj = 0; jj < 4; ++jj) {
            float invf = exp2f(-0.20762050f * (float)(d0 + jj));  // 10000^{-d/64}
            float ang = (float)(t0 + tl) * invf;
            float sn, cs;
            __sincosf(ang, &sn, &cs);
            kl[jj] = f2bf(ka[jj] * cs - kb[jj] * sn);
            kh[jj] = f2bf(kb[jj] * cs + ka[jj] * sn);
        }
        *reinterpret_cast<ushort4*>(Kr + gbase + d0)      = ushort4{kl[0], kl[1], kl[2], kl[3]};
        *reinterpret_cast<ushort4*>(Kr + gbase + d0 + 64) = ushort4{kh[0], kh[1], kh[2], kh[3]};
        int cc = tl >> 3, tr = tl & 7;            // 16B chunk + offset within
        #pragma unroll
        for (int jj = 0; jj < 4; ++jj) {
            int dA = d0 + jj, dB = d0 + 64 + jj;
            Klds[dA * 128 + ((cc ^ (dA & 15)) * 8) + tr] = kl[jj];
            Klds[dB * 128 + ((cc ^ (dB & 15)) * 8) + tr] = kh[jj];
            Vlds[dA * 128 + ((cc ^ (dA & 15)) * 8) + tr] = f2bf(va[jj]);
            Vlds[dB * 128 + ((cc ^ (dB & 15)) * 8) + tr] = f2bf(vb[jj]);
        }
    }
    __syncthreads();

    // ---- write Vt [B][D][S] from LDS (coalesced 16B chunks along t) ----
    #pragma unroll
    for (int it = 0; it < 8; ++it) {
        int e = it * 256 + tid;
        int d = e >> 4;                           // 0..127
        int cc = e & 15;
        const bf16x8 v8 = *reinterpret_cast<const bf16x8*>(
            &Vlds[d * 128 + ((cc ^ (d & 15)) * 8)]);
        *reinterpret_cast<bf16x8*>(
            Vt + ((size_t)(b * D_ + d)) * S_ + t0 + cc * 8) = v8;
    }

    // ---- G half-partial: D[dp][d] = sum_t V[t][dp] K[t][d], t over 128 ----
    const int w = tid >> 6, l = tid & 63, g = l >> 4, n = l & 15;
    f32x4 acc[2][8];
    #pragma unroll
    for (int dr = 0; dr < 2; ++dr)
        #pragma unroll
        for (int dc = 0; dc < 8; ++dc) acc[dr][dc] = f32x4{0.f, 0.f, 0.f, 0.f};

    #pragma unroll
    for (int ki = 0; ki < 4; ++ki) {
        bf16x8 a[2];
        #pragma unroll
        for (int dr = 0; dr < 2; ++dr) {
            int row = 32 * w + 16 * dr + n;       // row&15 == n
            a[dr] = *reinterpret_cast<const bf16x8*>(
                &Vlds[row * 128 + (((4 * ki + g) ^ n) * 8)]);
        }
        #pragma unroll
        for (int dc = 0; dc < 8; ++dc) {
            int row = dc * 16 + n;
            const bf16x8 bb = *reinterpret_cast<const bf16x8*>(
                &Klds[row * 128 + (((4 * ki + g) ^ n) * 8)]);
            acc[0][dc] = __builtin_amdgcn_mfma_f32_16x16x32_bf16(a[0], bb, acc[0][dc], 0, 0, 0);
            acc[1][dc] = __builtin_amdgcn_mfma_f32_16x16x32_bf16(a[1], bb, acc[1][dc], 0, 0, 0);
        }
    }

    float* out = P1 + (size_t)((b * NC + c) * 2 + half) * D_ * D_;
    #pragma unroll
    for (int dr = 0; dr < 2; ++dr)
        #pragma unroll
        for (int dc = 0; dc < 8; ++dc)
            #pragma unroll
            for (int rr = 0; rr < 4; ++rr)
                out[(size_t)(32 * w + 16 * dr + 4 * g + rr) * D_ + dc * 16 + n]
                    = acc[dr][dc][rr];
}

// ---------------------------------------------------------------------------
// prefix: exclusive prefix over chunk partials (2 halves each); single bf16 H.
//   thread -> (b,dp,d), d = gid&127 -> all reads/writes coalesced.
// ---------------------------------------------------------------------------
__global__ __launch_bounds__(256) void prefix(const float* __restrict__ P1,
                                              unsigned short* __restrict__ Hhi) {
    int gid = blockIdx.x * 256 + threadIdx.x;     // 0 .. 131071
    int d  = gid & 127;
    int dp = (gid >> 7) & 127;
    int b  = gid >> 14;
    float run = 0.f;
    #pragma unroll
    for (int c = 0; c < NC; ++c) {
        size_t hidx = ((size_t)(b * NC + c) * D_ + dp) * D_ + d;
        Hhi[hidx] = f2bf(run);
        size_t p = ((size_t)((b * NC + c) * 2) * D_ + dp) * D_ + d;
        run += P1[p];
        run += P1[p + (size_t)D_ * D_];
    }
}

// ---------------------------------------------------------------------------
// pass2: O_c = Qr_c . H_c (inter)  +  causal(Qr_c.Kr_c^T).V_c (intra).
//   Q RoPE'd in-register from f32. 512 blocks = 4 pp-groups (perm {3,2,0,1})
//   x 128 (b,c); 4 waves x 16 rows. Intra: K/V double-buffered (64KB),
//   counted-vmcnt skeleton. Unchanged from round 15 (passing).
// ---------------------------------------------------------------------------
__global__ __launch_bounds__(256, 2) void pass2(const float* __restrict__ Q,
                                                const unsigned short* __restrict__ Kr,
                                                const unsigned short* __restrict__ Vt,
                                                const unsigned short* __restrict__ Hhi,
                                                float* __restrict__ Out) {
    __shared__ unsigned short Kb[2][64 * 128];    // [t][d] swizzled chunks, 2x16KB
    __shared__ unsigned short Vb[2][128 * 64];    // [d][t] swizzled chunks, 2x16KB

    const int bid = blockIdx.x;
    const int ppmap[4] = {3, 2, 0, 1};
    const int pp = ppmap[bid >> 7];               // q-64-tile within chunk
    const int r2 = bid & 127;
    const int b  = r2 & 7;
    const int c  = r2 >> 3;                       // chunk 0..15
    const int qg = c * 4 + pp;
    const int c4 = c * 4;

    const int tid = threadIdx.x;
    const int wv = tid >> 6;
    const int l  = tid & 63;
    const int g  = l >> 4;
    const int n  = l & 15;

    // ---- hoist Q with in-register RoPE: lane holds Q[s][d=32ks+8g+j] ----
    bf16x8 qf[4];
    {
        const int s = qg * 64 + wv * 16 + n;
        const float* qp = Q + ((size_t)(b * S_ + s)) * D_ + 8 * g;
        float qv[4][8];
        #pragma unroll
        for (int ks = 0; ks < 4; ++ks) {
            *reinterpret_cast<float4*>(&qv[ks][0]) =
                *reinterpret_cast<const float4*>(qp + 32 * ks);
            *reinterpret_cast<float4*>(&qv[ks][4]) =
                *reinterpret_cast<const float4*>(qp + 32 * ks + 4);
        }
        unsigned short qb[4][8];
        #pragma unroll
        for (int hf = 0; hf < 2; ++hf)
            #pragma unroll
            for (int j = 0; j < 8; ++j) {
                int dm = 32 * hf + 8 * g + j;     // d mod 64
                float invf = exp2f(-0.20762050f * (float)dm);
                float ang = (float)s * invf;
                float sn, cs;
                __sincosf(ang, &sn, &cs);
                qb[hf][j]     = f2bf(qv[hf][j] * cs - qv[hf + 2][j] * sn);
                qb[hf + 2][j] = f2bf(qv[hf + 2][j] * cs + qv[hf][j] * sn);
            }
        #pragma unroll
        for (int ks = 0; ks < 4; ++ks) {
            bf16x8 f;
            #pragma unroll
            for (int j = 0; j < 8; ++j) f[j] = (short)qb[ks][j];
            qf[ks] = f;
        }
    }

    // K LDS chunk (t,cc) <- global chunk (t, cc^(t&15)); V chunk (d,cc) <- cc^(d&7)
    auto stage = [&](int bufs, int tg) {
        const unsigned short* kbase = Kr + ((size_t)(b * S_ + tg * 64)) * D_;
        #pragma unroll
        for (int i = 0; i < 4; ++i) {
            int ci = i * 256 + tid;
            int t = ci >> 4, cc = ci & 15;
            load_lds16(kbase + t * D_ + ((cc ^ (t & 15)) * 8), &Kb[bufs][ci * 8]);
        }
        const unsigned short* vbase = Vt + (size_t)b * D_ * S_ + (size_t)tg * 64;
        #pragma unroll
        for (int i = 0; i < 4; ++i) {
            int ci = i * 256 + tid;
            int d = ci >> 3, cc = ci & 7;
            load_lds16(vbase + (size_t)d * S_ + ((cc ^ (d & 7)) * 8), &Vb[bufs][ci * 8]);
        }
    };

    f32x4 o[8];
    #pragma unroll
    for (int df = 0; df < 8; ++df) o[df] = f32x4{0.f, 0.f, 0.f, 0.f};

    stage(0, c4);                                  // tile 0 (8 vm entries)
    if (pp >= 1) stage(1, c4 + 1);                 // tile 1 (8 more)

    // ---- inter: O += Q . H (single bf16 H); DMAs fly underneath ----
    {
        const unsigned short* hbase = Hhi + (size_t)(b * NC + c) * D_ * D_;
        #pragma unroll
        for (int ks = 0; ks < 4; ++ks) {
            #pragma unroll
            for (int df = 0; df < 8; ++df) {
                const bf16x8 hh = *reinterpret_cast<const bf16x8*>(
                    hbase + (size_t)(df * 16 + n) * D_ + 32 * ks + 8 * g);
                o[df] = __builtin_amdgcn_mfma_f32_16x16x32_bf16(qf[ks], hh, o[df], 0, 0, 0);
            }
        }
    }

    // ---- intra: kt = 0..pp causal tiles, double-buffered counted-vmcnt ----
    for (int kt = 0; kt <= pp; ++kt) {
        if (kt < pp) { WAIT_VMCNT_8; }             // tile kt landed; kt+1 in flight
        else         { WAIT_VMCNT_0; }
        BARRIER;

        const int bufc = kt & 1;

        // E^T = K.Q^T (swapped): lane(g,n) holds E[t=tf*16+4g+rr][s=qg*64+wv*16+n]
        f32x4 e[4];
        #pragma unroll
        for (int tf = 0; tf < 4; ++tf) e[tf] = f32x4{0.f, 0.f, 0.f, 0.f};
        __builtin_amdgcn_s_setprio(1);
        #pragma unroll
        for (int tf = 0; tf < 4; ++tf) {
            #pragma unroll
            for (int ks = 0; ks < 4; ++ks) {
                const bf16x8 kf = *reinterpret_cast<const bf16x8*>(
                    &Kb[bufc][(tf * 16 + n) * 128 + (((4 * ks + g) ^ n) * 8)]);
                e[tf] = __builtin_amdgcn_mfma_f32_16x16x32_bf16(kf, qf[ks], e[tf], 0, 0, 0);
            }
        }
        __builtin_amdgcn_s_setprio(0);

        if (kt == pp) {                            // diagonal tile: causal mask
            int s_glob = qg * 64 + wv * 16 + n;
            #pragma unroll
            for (int tf = 0; tf < 4; ++tf)
                #pragma unroll
                for (int rr = 0; rr < 4; ++rr) {
                    int t_glob = (c4 + kt) * 64 + tf * 16 + 4 * g + rr;
                    if (t_glob > s_glob) e[tf][rr] = 0.f;
                }
        }

        // E -> P A-frags in-register (8 cvt_pk + 8 permlane swaps, r4-verified)
        bf16x8 pf[2];
        {
            unsigned u0[4], u1[4];
            #pragma unroll
            for (int tf = 0; tf < 4; ++tf) {
                asm("v_cvt_pk_bf16_f32 %0, %1, %2"
                    : "=v"(u0[tf]) : "v"(e[tf][0]), "v"(e[tf][1]));
                asm("v_cvt_pk_bf16_f32 %0, %1, %2"
                    : "=v"(u1[tf]) : "v"(e[tf][2]), "v"(e[tf][3]));
            }
            #pragma unroll
            for (int ks = 0; ks < 2; ++ks) {
                unsigned a0 = u0[2 * ks], a1 = u0[2 * ks + 1];
                unsigned b0 = u1[2 * ks], b1 = u1[2 * ks + 1];
                asm("v_permlane32_swap_b32 %0, %1" : "+v"(a0), "+v"(a1));
                asm("v_permlane32_swap_b32 %0, %1" : "+v"(b0), "+v"(b1));
                asm("v_permlane16_swap_b32 %0, %1" : "+v"(a0), "+v"(a1));
                asm("v_permlane16_swap_b32 %0, %1" : "+v"(b0), "+v"(b1));
                pf[ks] = __builtin_bit_cast(bf16x8, u32x4{a0, b0, a1, b1});
            }
        }

        // O += P.V
        __builtin_amdgcn_s_setprio(1);
        #pragma unroll
        for (int df = 0; df < 8; ++df) {
            #pragma unroll
            for (int ks = 0; ks < 2; ++ks) {
                const bf16x8 vf = *reinterpret_cast<const bf16x8*>(
                    &Vb[bufc][(df * 16 + n) * 64 + (((4 * ks + g) ^ (n & 7)) * 8)]);
                o[df] = __builtin_amdgcn_mfma_f32_16x16x32_bf16(pf[ks], vf, o[df], 0, 0, 0);
            }
        }
        __builtin_amdgcn_s_setprio(0);

        BARRIER;                                   // all waves done reading bufc

        if (kt + 2 <= pp) stage(bufc, c4 + kt + 2);
    }

    // ---- epilogue: exclusive rows -> plain stores ----
    #pragma unroll
    for (int df = 0; df < 8; ++df)
        #pragma unroll
        for (int rr = 0; rr < 4; ++rr) {
            int srow = qg * 64 + wv * 16 + 4 * g + rr;
            Out[((size_t)(b * S_ + srow)) * D_ + df * 16 + n] = o[df][rr];
        }
}

// ---------------------------------------------------------------------------
extern "C" void kernel_launch(void* const* d_in, const int* in_sizes, int n_in,
                              void* d_out, int out_size, void* d_ws, size_t ws_size,
                              hipStream_t stream) {
    const float* Q = (const float*)d_in[0];
    const float* K = (const float*)d_in[1];
    const float* V = (const float*)d_in[2];

    const size_t NE = (size_t)B_ * S_ * D_;       // 4.19M elems
    unsigned short* Kr = (unsigned short*)d_ws;                    // 8 MB
    unsigned short* Vt = Kr + NE;                                  // 8 MB
    float*          P1 = (float*)(Vt + NE);                        // 16 MB f32 (2 halves)
    unsigned short* Hhi = (unsigned short*)(P1 + (size_t)B_ * NC * 2 * D_ * D_); // 4 MB

    fusedA<<<256, 256, 0, stream>>>(K, V, Kr, Vt, P1);
    prefix<<<512, 256, 0, stream>>>(P1, Hhi);
    pass2 <<<512, 256, 0, stream>>>(Q, Kr, Vt, Hhi, (float*)d_out);
}